// Round 18
// baseline (99.466 us; speedup 1.0000x reference)
//
#include <hip/hip_runtime.h>
#include <hip/hip_bf16.h>
#include <math.h>

#define B_ 4
#define DIM_ 256
#define H_ 128
#define W_ 128
#define HW_ (H_ * W_)
#define AD_ 64
#define HEADS_ 4
#define HD_ 16
#define WS_ 5
#define PAD_ 2

typedef __attribute__((ext_vector_type(8))) short short8;
typedef __attribute__((ext_vector_type(4))) float f32x4;
typedef __attribute__((ext_vector_type(4))) unsigned int u32x4;

__device__ __forceinline__ ushort f2bf(float f) {
    unsigned u = __builtin_bit_cast(unsigned, f);
    unsigned r = u + 0x7FFFu + ((u >> 16) & 1u);
    return (ushort)(r >> 16);
}
__device__ __forceinline__ float bf2f(ushort h) {
    return __builtin_bit_cast(float, (unsigned)h << 16);
}

// Truncation-based hi/lo split of an f32 pair into packed bf16 pairs.
__device__ __forceinline__ void splitpair(float x0, float x1,
                                          unsigned& hp, unsigned& lp) {
    unsigned u0 = __builtin_bit_cast(unsigned, x0);
    unsigned u1 = __builtin_bit_cast(unsigned, x1);
    hp = __builtin_amdgcn_perm(u1, u0, 0x07060302u);   // [u0.hi16, u1.hi16]
    float r0 = x0 - __builtin_bit_cast(float, u0 & 0xFFFF0000u);
    float r1 = x1 - __builtin_bit_cast(float, u1 & 0xFFFF0000u);
    lp = __builtin_amdgcn_perm(__builtin_bit_cast(unsigned, r1),
                               __builtin_bit_cast(unsigned, r0), 0x07060302u);
}

// async global->LDS, 16B per lane. LDS dest must be wave-uniform base + lane*16.
__device__ __forceinline__ void gl16(const void* g, void* l) {
    __builtin_amdgcn_global_load_lds(
        (const __attribute__((address_space(1))) unsigned int*)g,
        (__attribute__((address_space(3))) unsigned int*)l, 16, 0, 0);
}

// ---------------- prep: fragment-ordered bf16 hi/lo weights (Q/K/V/O) --------
__global__ __launch_bounds__(256) void k_prep(
    const float* __restrict__ Wq, const float* __restrict__ Wk,
    const float* __restrict__ Wv, const float* __restrict__ Wo,
    ushort* __restrict__ WfQh, ushort* __restrict__ WfQl,
    ushort* __restrict__ WfKVh, ushort* __restrict__ WfKVl,
    ushort* __restrict__ WoFh, ushort* __restrict__ WoFl)
{
    int i = blockIdx.x * 256 + threadIdx.x;          // 0 .. 49151
    if (i < 16384) {                                 // Q frags: 4mt*8kc*64l*8j
        int j = i & 7, l = (i >> 3) & 63, kc = (i >> 9) & 7, mt = i >> 12;
        int o = mt * 16 + (l & 15);
        int c = kc * 32 + ((l >> 4) & 3) * 8 + j;
        float wv = Wq[o * DIM_ + c];
        ushort h = f2bf(wv);
        WfQh[i] = h;
        WfQl[i] = f2bf(wv - bf2f(h));
        // Wo frags: 16 mtg * 2 kc * 64 l * 8 j (K=64)
        int kco = (i >> 9) & 1, mtg = i >> 10;
        int oo = mtg * 16 + (l & 15);
        int co = kco * 32 + ((l >> 4) & 3) * 8 + j;
        float wo = Wo[oo * AD_ + co];
        ushort ho = f2bf(wo);
        WoFh[i] = ho;
        WoFl[i] = f2bf(wo - bf2f(ho));
    } else if (i < 49152) {                          // KV frags: 8mt (K:0-3, V:4-7)
        int ii = i - 16384;
        int j = ii & 7, l = (ii >> 3) & 63, kc = (ii >> 9) & 7, mt = ii >> 12;
        const float* Ws = (mt < 4) ? Wk : Wv;
        int o = (mt & 3) * 16 + (l & 15);
        int c = kc * 32 + ((l >> 4) & 3) * 8 + j;
        float wv = Ws[o * DIM_ + c];
        ushort h = f2bf(wv);
        WfKVh[ii] = h;
        WfKVl[ii] = f2bf(wv - bf2f(h));
    }
}

// convert one 32c x (2x16px) B tile from a wave's LDS X subtile
__device__ __forceinline__ void conv_b(const float* Xw, int lr, int kg,
                                       short8* bh, short8* bl)
{
#pragma unroll
    for (int nt = 0; nt < 2; ++nt) {
        u32x4 h, l;
#pragma unroll
        for (int jp = 0; jp < 4; ++jp) {
            float x0 = Xw[(kg * 8 + 2 * jp    ) * 32 + nt * 16 + lr];
            float x1 = Xw[(kg * 8 + 2 * jp + 1) * 32 + nt * 16 + lr];
            unsigned hp, lp;
            splitpair(x0, x1, hp, lp);
            h[jp] = hp;
            l[jp] = lp;
        }
        bh[nt] = __builtin_bit_cast(short8, h);
        bl[nt] = __builtin_bit_cast(short8, l);
    }
}

// ---------------- QKV projection v17: v15 pipeline + XCD-affinity remap ------
// All three roles of pixel-group g map to bids 8 apart -> same XCD; K(g) and
// V(g) stream the same kv_in slab on one L2. (R17: 68 -> ~60 us.)
__global__ __launch_bounds__(256, 3) void k_qkv(
    const float* __restrict__ q_in, const float* __restrict__ kv_in,
    const ushort* __restrict__ WfQh, const ushort* __restrict__ WfQl,
    const ushort* __restrict__ WfKVh, const ushort* __restrict__ WfKVl,
    float* __restrict__ qh, float* __restrict__ kh, float* __restrict__ vv)
{
    __shared__ float Xl[3][4][32 * 32];    // [buf][wave][c*32+px] = 48 KB

    int bid  = blockIdx.x;
    int xcd  = bid & 7;                    // this block's XCD (round-robin)
    int slot = bid >> 3;                   // 0..191
    int role = slot % 3;                   // 0=Q 1=K 2=V (adjacent slots = same g)
    int g    = (slot / 3) * 8 + xcd;       // pixel group 0..511
    int b    = g >> 7;                     // batch (128 groups per batch)
    int p0   = (g & 127) * 128;            // pixel base within batch

    const float*  xsrc = (role == 0) ? q_in : kv_in;
    const ushort* Wh = (role == 0) ? WfQh : (role == 1) ? WfKVh : (WfKVh + 16384);
    const ushort* Wl = (role == 0) ? WfQl : (role == 1) ? WfKVl : (WfKVl + 16384);
    float* outp = (role == 0) ? qh : (role == 1) ? kh : vv;
    bool norm = (role < 2);                // uniform per block

    int tid  = threadIdx.x;
    int lane = tid & 63;
    int wid  = __builtin_amdgcn_readfirstlane(tid >> 6);
    int lr = lane & 15, kg = lane >> 4;

    const float* xw = xsrc + ((size_t)b * DIM_ << 14) + p0 + wid * 32;

    short8 ah[2][4], al[2][4];             // A-frag reg double-buffer

    // ---- prologue: X(0) -> buf0, A(0) -> set0, X(1) -> buf1
#pragma unroll
    for (int i = 0; i < 4; ++i) {
        int s = i * 64 + lane;             // r = s>>3 (c-row), seg = s&7
        gl16(xw + (size_t)(s >> 3) * HW_ + (s & 7) * 4, &Xl[0][wid][s * 4]);
    }
#pragma unroll
    for (int mt = 0; mt < 4; ++mt) {
        int off = (((mt * 8 + 0) << 6) + lane) * 8;
        ah[0][mt] = *(const short8*)(Wh + off);
        al[0][mt] = *(const short8*)(Wl + off);
    }
#pragma unroll
    for (int i = 0; i < 4; ++i) {
        int s = i * 64 + lane;
        gl16(xw + (size_t)(32 + (s >> 3)) * HW_ + (s & 7) * 4, &Xl[1][wid][s * 4]);
    }

    f32x4 acc[4][2];
#pragma unroll
    for (int mt = 0; mt < 4; ++mt)
#pragma unroll
        for (int nt = 0; nt < 2; ++nt) {
            f32x4 z = {0.f, 0.f, 0.f, 0.f};
            acc[mt][nt] = z;
        }

#pragma unroll
    for (int kc = 0; kc < 8; ++kc) {
        const int cs = kc & 1, ns = cs ^ 1;

        if (kc < 7) {                      // A(kc+1) -> other reg set (1-ahead)
#pragma unroll
            for (int mt = 0; mt < 4; ++mt) {
                int off = (((mt * 8 + kc + 1) << 6) + lane) * 8;
                ah[ns][mt] = *(const short8*)(Wh + off);
                al[ns][mt] = *(const short8*)(Wl + off);
            }
        }
        if (kc < 6) {                      // X(kc+2) -> buf (kc+2)%3 (2-ahead)
#pragma unroll
            for (int i = 0; i < 4; ++i) {
                int s = i * 64 + lane;
                gl16(xw + (size_t)((kc + 2) * 32 + (s >> 3)) * HW_ + (s & 7) * 4,
                     &Xl[(kc + 2) % 3][wid][s * 4]);
            }
        }

        // drain exactly [X(kc), A(kc)]; keep [X(kc+1), A(kc+1), X(kc+2)] flying
        if (kc < 6)       asm volatile("s_waitcnt vmcnt(16)" ::: "memory");
        else if (kc == 6) asm volatile("s_waitcnt vmcnt(12)" ::: "memory");
        else              asm volatile("s_waitcnt vmcnt(0)"  ::: "memory");
        __builtin_amdgcn_sched_barrier(0);

        // ---- compute chunk kc from LDS buf kc%3 and reg set cs
        short8 bh[2], bl[2];
        conv_b(&Xl[kc % 3][wid][0], lr, kg, bh, bl);
#pragma unroll
        for (int mt = 0; mt < 4; ++mt) {
#pragma unroll
            for (int nt = 0; nt < 2; ++nt) {
                acc[mt][nt] = __builtin_amdgcn_mfma_f32_16x16x32_bf16(ah[cs][mt], bh[nt], acc[mt][nt], 0, 0, 0);
                acc[mt][nt] = __builtin_amdgcn_mfma_f32_16x16x32_bf16(ah[cs][mt], bl[nt], acc[mt][nt], 0, 0, 0);
                acc[mt][nt] = __builtin_amdgcn_mfma_f32_16x16x32_bf16(al[cs][mt], bh[nt], acc[mt][nt], 0, 0, 0);
            }
        }
    }

    // ---- epilogue: l2norm + store
    int pr = p0 + wid * 32;
#pragma unroll
    for (int mt = 0; mt < 4; ++mt) {
#pragma unroll
        for (int nt = 0; nt < 2; ++nt) {
            f32x4 v = acc[mt][nt];
            if (norm) {                    // l2norm over the head's 16 rows
                float s = v.x * v.x + v.y * v.y + v.z * v.z + v.w * v.w;
                s += __shfl_xor(s, 16);    // lanes {lr, lr+16, lr+32, lr+48}
                s += __shfl_xor(s, 32);
                float inv = 1.f / fmaxf(sqrtf(s), 1e-12f);
                v.x *= inv; v.y *= inv; v.z *= inv; v.w *= inv;
            }
            float* dst = outp
                + (((size_t)(b * HEADS_ + mt) << 14) + pr + nt * 16 + lr) * HD_ + kg * 4;
            *(f32x4*)dst = v;
        }
    }
}

__device__ __forceinline__ int refl(int i, int n) {
    if (i < 0) i = -i;
    if (i >= n) i = 2 * n - 2 - i;
    return i;
}

// ---------------- FUSED attention + output projection ------------------------
// v18 change: CONSUMER-ALIGNED XCD swizzle. k_qkv's remap puts pixel-group
// g = x (mod 8) on XCD x, so its qh/kh/vv slabs end in XCD x's L2. The old
// attn swizzle gave XCD x a contiguous half-batch slab (produced elsewhere ->
// L3 reads). New map: x = bid&7, m = bid>>3, swz = (m>>2)*32 + x*4 + (m&3)
// (bijective; parent 128-px group swz>>2 = (m>>2)*8 + x = x mod 8) -> each
// attn block reads intermediates produced on ITS OWN XCD's L2.
__global__ __launch_bounds__(256) void k_attn(
    const float* __restrict__ qh, const float* __restrict__ kh,
    const float* __restrict__ vv, const ushort* __restrict__ WoFh,
    const ushort* __restrict__ WoFl, float* __restrict__ out)
{
    __shared__ float aoL[32][65];          // +1 pad: conflict-free writes

    int bid = blockIdx.x;
    int xcd = bid & 7;
    int mm  = bid >> 3;                    // 0..255
    int swz = (mm >> 2) * 32 + xcd * 4 + (mm & 3);   // bijective on 2048
    int b   = swz >> 9;                    // batch
    int p0  = (swz & 511) * 32;            // 32-px group base
    int tid = threadIdx.x;
    int lane = tid & 63;
    int w   = __builtin_amdgcn_readfirstlane(tid >> 6);  // head / oc-quarter
    int t   = lane >> 5;                   // d-half: 0 or 1
    int pl  = lane & 31;

    int p  = p0 + pl;
    int bh = b * HEADS_ + w;
    int y = p >> 7, x = p & (W_ - 1);
    int to = t * 8;

    const float* qp = qh + ((size_t)bh * HW_ + p) * HD_ + to;
    float4 qa = *(const float4*)(qp + 0);
    float4 qb = *(const float4*)(qp + 4);

    float logit[WS_ * WS_];
    int   nidx [WS_ * WS_];
#pragma unroll
    for (int i = 0; i < WS_; ++i) {
        int ry = refl(y + i - PAD_, H_);
#pragma unroll
        for (int j = 0; j < WS_; ++j) {
            int rx = refl(x + j - PAD_, W_);
            int np_ = ry * W_ + rx;
            nidx[i*WS_ + j] = np_;
            const float* kp = kh + ((size_t)bh * HW_ + np_) * HD_ + to;
            float4 ka = *(const float4*)(kp + 0);
            float4 kb = *(const float4*)(kp + 4);
            float d = 0.f;
            d = fmaf(qa.x, ka.x, d); d = fmaf(qa.y, ka.y, d);
            d = fmaf(qa.z, ka.z, d); d = fmaf(qa.w, ka.w, d);
            d = fmaf(qb.x, kb.x, d); d = fmaf(qb.y, kb.y, d);
            d = fmaf(qb.z, kb.z, d); d = fmaf(qb.w, kb.w, d);
            logit[i*WS_ + j] = d + __shfl_xor(d, 32);   // combine d-halves
        }
    }

    float m = logit[0];
#pragma unroll
    for (int q = 1; q < WS_*WS_; ++q) m = fmaxf(m, logit[q]);
    float s = 0.f;
#pragma unroll
    for (int q = 0; q < WS_*WS_; ++q) { float e = expf(logit[q] - m); logit[q] = e; s += e; }
    float invs = 1.f / s;

    float a[8];
#pragma unroll
    for (int d = 0; d < 8; ++d) a[d] = 0.f;
#pragma unroll
    for (int q = 0; q < WS_*WS_; ++q) {
        float wt = logit[q] * invs;
        const float* vp = vv + ((size_t)bh * HW_ + nidx[q]) * HD_ + to;
        float4 va = *(const float4*)(vp + 0);
        float4 vb = *(const float4*)(vp + 4);
        a[0] = fmaf(wt, va.x, a[0]); a[1] = fmaf(wt, va.y, a[1]);
        a[2] = fmaf(wt, va.z, a[2]); a[3] = fmaf(wt, va.w, a[3]);
        a[4] = fmaf(wt, vb.x, a[4]); a[5] = fmaf(wt, vb.y, a[5]);
        a[6] = fmaf(wt, vb.z, a[6]); a[7] = fmaf(wt, vb.w, a[7]);
    }

    // attn result -> LDS tile (row = px, col = attn channel h*16+d)
#pragma unroll
    for (int j = 0; j < 8; ++j)
        aoL[pl][w * HD_ + to + j] = a[j];
    __syncthreads();

    // ---- oproj phase: wave w -> oc [w*64, w*64+64), 32 px, K=64 in 2 chunks
    int lr = lane & 15, kg = lane >> 4;

    f32x4 acc[4][2];
#pragma unroll
    for (int mt = 0; mt < 4; ++mt)
#pragma unroll
        for (int nt = 0; nt < 2; ++nt) {
            f32x4 z = {0.f, 0.f, 0.f, 0.f};
            acc[mt][nt] = z;
        }

#pragma unroll
    for (int kc = 0; kc < 2; ++kc) {
        short8 bh8[2], bl8[2];
#pragma unroll
        for (int nt = 0; nt < 2; ++nt) {
            u32x4 hh, ll;
#pragma unroll
            for (int jp = 0; jp < 4; ++jp) {
                float x0 = aoL[nt * 16 + lr][kc * 32 + kg * 8 + 2 * jp];
                float x1 = aoL[nt * 16 + lr][kc * 32 + kg * 8 + 2 * jp + 1];
                unsigned hp, lp;
                splitpair(x0, x1, hp, lp);
                hh[jp] = hp;
                ll[jp] = lp;
            }
            bh8[nt] = __builtin_bit_cast(short8, hh);
            bl8[nt] = __builtin_bit_cast(short8, ll);
        }
#pragma unroll
        for (int mt = 0; mt < 4; ++mt) {
            int mtg = w * 4 + mt;          // global 16-oc tile, 0..15
            short8 ah = *(const short8*)(WoFh + (((mtg * 2 + kc) << 6) + lane) * 8);
            short8 al = *(const short8*)(WoFl + (((mtg * 2 + kc) << 6) + lane) * 8);
#pragma unroll
            for (int nt = 0; nt < 2; ++nt) {
                acc[mt][nt] = __builtin_amdgcn_mfma_f32_16x16x32_bf16(ah, bh8[nt], acc[mt][nt], 0, 0, 0);
                acc[mt][nt] = __builtin_amdgcn_mfma_f32_16x16x32_bf16(ah, bl8[nt], acc[mt][nt], 0, 0, 0);
                acc[mt][nt] = __builtin_amdgcn_mfma_f32_16x16x32_bf16(al, bh8[nt], acc[mt][nt], 0, 0, 0);
            }
        }
    }

#pragma unroll
    for (int mt = 0; mt < 4; ++mt) {
#pragma unroll
        for (int nt = 0; nt < 2; ++nt) {
            int oc = w * 64 + mt * 16 + kg * 4;
            int px = p0 + nt * 16 + lr;
            float* op = out + (size_t)b * DIM_ * HW_ + (size_t)oc * HW_ + px;
            op[0 * HW_] = acc[mt][nt].x;
            op[1 * HW_] = acc[mt][nt].y;
            op[2 * HW_] = acc[mt][nt].z;
            op[3 * HW_] = acc[mt][nt].w;
        }
    }
}

extern "C" void kernel_launch(void* const* d_in, const int* in_sizes, int n_in,
                              void* d_out, int out_size, void* d_ws, size_t ws_size,
                              hipStream_t stream) {
    const float* q_in  = (const float*)d_in[0];
    const float* kv_in = (const float*)d_in[1];
    const float* Wq    = (const float*)d_in[2];
    const float* Wk    = (const float*)d_in[3];
    const float* Wv    = (const float*)d_in[4];
    const float* Wo    = (const float*)d_in[5];
    float* out = (float*)d_out;

    float* wsf = (float*)d_ws;
    ushort* u     = (ushort*)wsf;
    ushort* WfQh  = u;             // 16384 shorts
    ushort* WfQl  = u + 16384;     // 16384
    ushort* WfKVh = u + 32768;     // 32768 (K: first 16384, V: last 16384)
    ushort* WfKVl = u + 65536;     // 32768
    ushort* WoFh  = u + 98304;     // 16384
    ushort* WoFl  = u + 114688;    // 16384 (ends 131072 sh = 65536 floats)
    size_t tens = (size_t)B_ * HEADS_ * HW_ * HD_;   // 4,194,304 floats
    float* qh = wsf + 65536;
    float* kh = qh + tens;
    float* vv = kh + tens;

    k_prep<<<dim3(192), dim3(256), 0, stream>>>(Wq, Wk, Wv, Wo,
                                                WfQh, WfQl, WfKVh, WfKVl, WoFh, WoFl);
    k_qkv<<<dim3(1536), dim3(256), 0, stream>>>(q_in, kv_in,
                                                WfQh, WfQl, WfKVh, WfKVl, qh, kh, vv);
    k_attn<<<dim3(2048), dim3(256), 0, stream>>>(qh, kh, vv, WoFh, WoFl, out);
}

// Round 19
// 97.728 us; speedup vs baseline: 1.0178x; 1.0178x over previous
//
#include <hip/hip_runtime.h>
#include <hip/hip_bf16.h>
#include <math.h>

#define B_ 4
#define DIM_ 256
#define H_ 128
#define W_ 128
#define HW_ (H_ * W_)
#define AD_ 64
#define HEADS_ 4
#define HD_ 16
#define WS_ 5
#define PAD_ 2

typedef __attribute__((ext_vector_type(8))) short short8;
typedef __attribute__((ext_vector_type(4))) float f32x4;
typedef __attribute__((ext_vector_type(4))) unsigned int u32x4;

__device__ __forceinline__ ushort f2bf(float f) {
    unsigned u = __builtin_bit_cast(unsigned, f);
    unsigned r = u + 0x7FFFu + ((u >> 16) & 1u);
    return (ushort)(r >> 16);
}
__device__ __forceinline__ float bf2f(ushort h) {
    return __builtin_bit_cast(float, (unsigned)h << 16);
}

// Truncation-based hi/lo split of an f32 pair into packed bf16 pairs.
__device__ __forceinline__ void splitpair(float x0, float x1,
                                          unsigned& hp, unsigned& lp) {
    unsigned u0 = __builtin_bit_cast(unsigned, x0);
    unsigned u1 = __builtin_bit_cast(unsigned, x1);
    hp = __builtin_amdgcn_perm(u1, u0, 0x07060302u);   // [u0.hi16, u1.hi16]
    float r0 = x0 - __builtin_bit_cast(float, u0 & 0xFFFF0000u);
    float r1 = x1 - __builtin_bit_cast(float, u1 & 0xFFFF0000u);
    lp = __builtin_amdgcn_perm(__builtin_bit_cast(unsigned, r1),
                               __builtin_bit_cast(unsigned, r0), 0x07060302u);
}

// async global->LDS, 16B per lane. LDS dest must be wave-uniform base + lane*16.
__device__ __forceinline__ void gl16(const void* g, void* l) {
    __builtin_amdgcn_global_load_lds(
        (const __attribute__((address_space(1))) unsigned int*)g,
        (__attribute__((address_space(3))) unsigned int*)l, 16, 0, 0);
}

// ---------------- prep: fragment-ordered bf16 hi/lo weights (Q/K/V/O) --------
__global__ __launch_bounds__(256) void k_prep(
    const float* __restrict__ Wq, const float* __restrict__ Wk,
    const float* __restrict__ Wv, const float* __restrict__ Wo,
    ushort* __restrict__ WfQh, ushort* __restrict__ WfQl,
    ushort* __restrict__ WfKVh, ushort* __restrict__ WfKVl,
    ushort* __restrict__ WoFh, ushort* __restrict__ WoFl)
{
    int i = blockIdx.x * 256 + threadIdx.x;          // 0 .. 49151
    if (i < 16384) {                                 // Q frags: 4mt*8kc*64l*8j
        int j = i & 7, l = (i >> 3) & 63, kc = (i >> 9) & 7, mt = i >> 12;
        int o = mt * 16 + (l & 15);
        int c = kc * 32 + ((l >> 4) & 3) * 8 + j;
        float wv = Wq[o * DIM_ + c];
        ushort h = f2bf(wv);
        WfQh[i] = h;
        WfQl[i] = f2bf(wv - bf2f(h));
        // Wo frags: 16 mtg * 2 kc * 64 l * 8 j (K=64)
        int kco = (i >> 9) & 1, mtg = i >> 10;
        int oo = mtg * 16 + (l & 15);
        int co = kco * 32 + ((l >> 4) & 3) * 8 + j;
        float wo = Wo[oo * AD_ + co];
        ushort ho = f2bf(wo);
        WoFh[i] = ho;
        WoFl[i] = f2bf(wo - bf2f(ho));
    } else if (i < 49152) {                          // KV frags: 8mt (K:0-3, V:4-7)
        int ii = i - 16384;
        int j = ii & 7, l = (ii >> 3) & 63, kc = (ii >> 9) & 7, mt = ii >> 12;
        const float* Ws = (mt < 4) ? Wk : Wv;
        int o = (mt & 3) * 16 + (l & 15);
        int c = kc * 32 + ((l >> 4) & 3) * 8 + j;
        float wv = Ws[o * DIM_ + c];
        ushort h = f2bf(wv);
        WfKVh[ii] = h;
        WfKVl[ii] = f2bf(wv - bf2f(h));
    }
}

// convert one 32c x (2x16px) B tile from a wave's LDS X subtile
__device__ __forceinline__ void conv_b(const float* Xw, int lr, int kg,
                                       short8* bh, short8* bl)
{
#pragma unroll
    for (int nt = 0; nt < 2; ++nt) {
        u32x4 h, l;
#pragma unroll
        for (int jp = 0; jp < 4; ++jp) {
            float x0 = Xw[(kg * 8 + 2 * jp    ) * 32 + nt * 16 + lr];
            float x1 = Xw[(kg * 8 + 2 * jp + 1) * 32 + nt * 16 + lr];
            unsigned hp, lp;
            splitpair(x0, x1, hp, lp);
            h[jp] = hp;
            l[jp] = lp;
        }
        bh[nt] = __builtin_bit_cast(short8, h);
        bl[nt] = __builtin_bit_cast(short8, l);
    }
}

// ---------------- QKV projection v19: contiguous per-XCD group slabs ---------
// R17's mechanism kept: Q/K/V roles of group g on consecutive same-XCD slots
// (K and V stream the same kv_in slab on one L2). Change vs v17: XCD x now
// owns a CONTIGUOUS slab of groups g in [64x, 64x+64) (was g = x mod 8,
// interleaved). This aligns the producer XCD of qh/kh/vv with the attn
// kernel's contiguous-slab swizzle (R17 version, restored below) so the
// consumer reads intermediates from its own L2 AND keeps vertical-halo
// locality (R18's mod-8 attn swizzle broke halos: FETCH 26->90 MB).
// bid = ((g%64)*3 + role)*8 + (g/64)  — bijective on [0,1536).
__global__ __launch_bounds__(256, 3) void k_qkv(
    const float* __restrict__ q_in, const float* __restrict__ kv_in,
    const ushort* __restrict__ WfQh, const ushort* __restrict__ WfQl,
    const ushort* __restrict__ WfKVh, const ushort* __restrict__ WfKVl,
    float* __restrict__ qh, float* __restrict__ kh, float* __restrict__ vv)
{
    __shared__ float Xl[3][4][32 * 32];    // [buf][wave][c*32+px] = 48 KB

    int bid  = blockIdx.x;
    int xcd  = bid & 7;                    // this block's XCD (round-robin)
    int slot = bid >> 3;                   // 0..191
    int role = slot % 3;                   // 0=Q 1=K 2=V (adjacent slots = same g)
    int g    = xcd * 64 + slot / 3;        // contiguous 64-group slab per XCD
    int b    = g >> 7;                     // batch (128 groups per batch)
    int p0   = (g & 127) * 128;            // pixel base within batch

    const float*  xsrc = (role == 0) ? q_in : kv_in;
    const ushort* Wh = (role == 0) ? WfQh : (role == 1) ? WfKVh : (WfKVh + 16384);
    const ushort* Wl = (role == 0) ? WfQl : (role == 1) ? WfKVl : (WfKVl + 16384);
    float* outp = (role == 0) ? qh : (role == 1) ? kh : vv;
    bool norm = (role < 2);                // uniform per block

    int tid  = threadIdx.x;
    int lane = tid & 63;
    int wid  = __builtin_amdgcn_readfirstlane(tid >> 6);
    int lr = lane & 15, kg = lane >> 4;

    const float* xw = xsrc + ((size_t)b * DIM_ << 14) + p0 + wid * 32;

    short8 ah[2][4], al[2][4];             // A-frag reg double-buffer

    // ---- prologue: X(0) -> buf0, A(0) -> set0, X(1) -> buf1
#pragma unroll
    for (int i = 0; i < 4; ++i) {
        int s = i * 64 + lane;             // r = s>>3 (c-row), seg = s&7
        gl16(xw + (size_t)(s >> 3) * HW_ + (s & 7) * 4, &Xl[0][wid][s * 4]);
    }
#pragma unroll
    for (int mt = 0; mt < 4; ++mt) {
        int off = (((mt * 8 + 0) << 6) + lane) * 8;
        ah[0][mt] = *(const short8*)(Wh + off);
        al[0][mt] = *(const short8*)(Wl + off);
    }
#pragma unroll
    for (int i = 0; i < 4; ++i) {
        int s = i * 64 + lane;
        gl16(xw + (size_t)(32 + (s >> 3)) * HW_ + (s & 7) * 4, &Xl[1][wid][s * 4]);
    }

    f32x4 acc[4][2];
#pragma unroll
    for (int mt = 0; mt < 4; ++mt)
#pragma unroll
        for (int nt = 0; nt < 2; ++nt) {
            f32x4 z = {0.f, 0.f, 0.f, 0.f};
            acc[mt][nt] = z;
        }

#pragma unroll
    for (int kc = 0; kc < 8; ++kc) {
        const int cs = kc & 1, ns = cs ^ 1;

        if (kc < 7) {                      // A(kc+1) -> other reg set (1-ahead)
#pragma unroll
            for (int mt = 0; mt < 4; ++mt) {
                int off = (((mt * 8 + kc + 1) << 6) + lane) * 8;
                ah[ns][mt] = *(const short8*)(Wh + off);
                al[ns][mt] = *(const short8*)(Wl + off);
            }
        }
        if (kc < 6) {                      // X(kc+2) -> buf (kc+2)%3 (2-ahead)
#pragma unroll
            for (int i = 0; i < 4; ++i) {
                int s = i * 64 + lane;
                gl16(xw + (size_t)((kc + 2) * 32 + (s >> 3)) * HW_ + (s & 7) * 4,
                     &Xl[(kc + 2) % 3][wid][s * 4]);
            }
        }

        // drain exactly [X(kc), A(kc)]; keep [X(kc+1), A(kc+1), X(kc+2)] flying
        if (kc < 6)       asm volatile("s_waitcnt vmcnt(16)" ::: "memory");
        else if (kc == 6) asm volatile("s_waitcnt vmcnt(12)" ::: "memory");
        else              asm volatile("s_waitcnt vmcnt(0)"  ::: "memory");
        __builtin_amdgcn_sched_barrier(0);

        // ---- compute chunk kc from LDS buf kc%3 and reg set cs
        short8 bh[2], bl[2];
        conv_b(&Xl[kc % 3][wid][0], lr, kg, bh, bl);
#pragma unroll
        for (int mt = 0; mt < 4; ++mt) {
#pragma unroll
            for (int nt = 0; nt < 2; ++nt) {
                acc[mt][nt] = __builtin_amdgcn_mfma_f32_16x16x32_bf16(ah[cs][mt], bh[nt], acc[mt][nt], 0, 0, 0);
                acc[mt][nt] = __builtin_amdgcn_mfma_f32_16x16x32_bf16(ah[cs][mt], bl[nt], acc[mt][nt], 0, 0, 0);
                acc[mt][nt] = __builtin_amdgcn_mfma_f32_16x16x32_bf16(al[cs][mt], bh[nt], acc[mt][nt], 0, 0, 0);
            }
        }
    }

    // ---- epilogue: l2norm + store
    int pr = p0 + wid * 32;
#pragma unroll
    for (int mt = 0; mt < 4; ++mt) {
#pragma unroll
        for (int nt = 0; nt < 2; ++nt) {
            f32x4 v = acc[mt][nt];
            if (norm) {                    // l2norm over the head's 16 rows
                float s = v.x * v.x + v.y * v.y + v.z * v.z + v.w * v.w;
                s += __shfl_xor(s, 16);    // lanes {lr, lr+16, lr+32, lr+48}
                s += __shfl_xor(s, 32);
                float inv = 1.f / fmaxf(sqrtf(s), 1e-12f);
                v.x *= inv; v.y *= inv; v.z *= inv; v.w *= inv;
            }
            float* dst = outp
                + (((size_t)(b * HEADS_ + mt) << 14) + pr + nt * 16 + lr) * HD_ + kg * 4;
            *(f32x4*)dst = v;
        }
    }
}

__device__ __forceinline__ int refl(int i, int n) {
    if (i < 0) i = -i;
    if (i >= n) i = 2 * n - 2 - i;
    return i;
}

// ---------------- FUSED attention + output projection ------------------------
// Attn swizzle: R17 contiguous-slab version (restored — R18's mod-8 variant
// broke vertical-halo locality, FETCH 26->90 MB). XCD x reads 32-px groups
// [256x, 256x+256) = 128-px groups [64x, 64x+64) — the exact slab k_qkv v19
// produced on XCD x: halo-local AND producer-aligned.
__global__ __launch_bounds__(256) void k_attn(
    const float* __restrict__ qh, const float* __restrict__ kh,
    const float* __restrict__ vv, const ushort* __restrict__ WoFh,
    const ushort* __restrict__ WoFl, float* __restrict__ out)
{
    __shared__ float aoL[32][65];          // +1 pad: conflict-free writes

    int bid = blockIdx.x;
    int swz = (bid & 7) * 256 + (bid >> 3);          // bijective on 2048
    int b   = swz >> 9;                    // batch
    int p0  = (swz & 511) * 32;            // 32-px group base
    int tid = threadIdx.x;
    int lane = tid & 63;
    int w   = __builtin_amdgcn_readfirstlane(tid >> 6);  // head / oc-quarter
    int t   = lane >> 5;                   // d-half: 0 or 1
    int pl  = lane & 31;

    int p  = p0 + pl;
    int bh = b * HEADS_ + w;
    int y = p >> 7, x = p & (W_ - 1);
    int to = t * 8;

    const float* qp = qh + ((size_t)bh * HW_ + p) * HD_ + to;
    float4 qa = *(const float4*)(qp + 0);
    float4 qb = *(const float4*)(qp + 4);

    float logit[WS_ * WS_];
    int   nidx [WS_ * WS_];
#pragma unroll
    for (int i = 0; i < WS_; ++i) {
        int ry = refl(y + i - PAD_, H_);
#pragma unroll
        for (int j = 0; j < WS_; ++j) {
            int rx = refl(x + j - PAD_, W_);
            int np_ = ry * W_ + rx;
            nidx[i*WS_ + j] = np_;
            const float* kp = kh + ((size_t)bh * HW_ + np_) * HD_ + to;
            float4 ka = *(const float4*)(kp + 0);
            float4 kb = *(const float4*)(kp + 4);
            float d = 0.f;
            d = fmaf(qa.x, ka.x, d); d = fmaf(qa.y, ka.y, d);
            d = fmaf(qa.z, ka.z, d); d = fmaf(qa.w, ka.w, d);
            d = fmaf(qb.x, kb.x, d); d = fmaf(qb.y, kb.y, d);
            d = fmaf(qb.z, kb.z, d); d = fmaf(qb.w, kb.w, d);
            logit[i*WS_ + j] = d + __shfl_xor(d, 32);   // combine d-halves
        }
    }

    float m = logit[0];
#pragma unroll
    for (int q = 1; q < WS_*WS_; ++q) m = fmaxf(m, logit[q]);
    float s = 0.f;
#pragma unroll
    for (int q = 0; q < WS_*WS_; ++q) { float e = expf(logit[q] - m); logit[q] = e; s += e; }
    float invs = 1.f / s;

    float a[8];
#pragma unroll
    for (int d = 0; d < 8; ++d) a[d] = 0.f;
#pragma unroll
    for (int q = 0; q < WS_*WS_; ++q) {
        float wt = logit[q] * invs;
        const float* vp = vv + ((size_t)bh * HW_ + nidx[q]) * HD_ + to;
        float4 va = *(const float4*)(vp + 0);
        float4 vb = *(const float4*)(vp + 4);
        a[0] = fmaf(wt, va.x, a[0]); a[1] = fmaf(wt, va.y, a[1]);
        a[2] = fmaf(wt, va.z, a[2]); a[3] = fmaf(wt, va.w, a[3]);
        a[4] = fmaf(wt, vb.x, a[4]); a[5] = fmaf(wt, vb.y, a[5]);
        a[6] = fmaf(wt, vb.z, a[6]); a[7] = fmaf(wt, vb.w, a[7]);
    }

    // attn result -> LDS tile (row = px, col = attn channel h*16+d)
#pragma unroll
    for (int j = 0; j < 8; ++j)
        aoL[pl][w * HD_ + to + j] = a[j];
    __syncthreads();

    // ---- oproj phase: wave w -> oc [w*64, w*64+64), 32 px, K=64 in 2 chunks
    int lr = lane & 15, kg = lane >> 4;

    f32x4 acc[4][2];
#pragma unroll
    for (int mt = 0; mt < 4; ++mt)
#pragma unroll
        for (int nt = 0; nt < 2; ++nt) {
            f32x4 z = {0.f, 0.f, 0.f, 0.f};
            acc[mt][nt] = z;
        }

#pragma unroll
    for (int kc = 0; kc < 2; ++kc) {
        short8 bh8[2], bl8[2];
#pragma unroll
        for (int nt = 0; nt < 2; ++nt) {
            u32x4 hh, ll;
#pragma unroll
            for (int jp = 0; jp < 4; ++jp) {
                float x0 = aoL[nt * 16 + lr][kc * 32 + kg * 8 + 2 * jp];
                float x1 = aoL[nt * 16 + lr][kc * 32 + kg * 8 + 2 * jp + 1];
                unsigned hp, lp;
                splitpair(x0, x1, hp, lp);
                hh[jp] = hp;
                ll[jp] = lp;
            }
            bh8[nt] = __builtin_bit_cast(short8, hh);
            bl8[nt] = __builtin_bit_cast(short8, ll);
        }
#pragma unroll
        for (int mt = 0; mt < 4; ++mt) {
            int mtg = w * 4 + mt;          // global 16-oc tile, 0..15
            short8 ah = *(const short8*)(WoFh + (((mtg * 2 + kc) << 6) + lane) * 8);
            short8 al = *(const short8*)(WoFl + (((mtg * 2 + kc) << 6) + lane) * 8);
#pragma unroll
            for (int nt = 0; nt < 2; ++nt) {
                acc[mt][nt] = __builtin_amdgcn_mfma_f32_16x16x32_bf16(ah, bh8[nt], acc[mt][nt], 0, 0, 0);
                acc[mt][nt] = __builtin_amdgcn_mfma_f32_16x16x32_bf16(ah, bl8[nt], acc[mt][nt], 0, 0, 0);
                acc[mt][nt] = __builtin_amdgcn_mfma_f32_16x16x32_bf16(al, bh8[nt], acc[mt][nt], 0, 0, 0);
            }
        }
    }

#pragma unroll
    for (int mt = 0; mt < 4; ++mt) {
#pragma unroll
        for (int nt = 0; nt < 2; ++nt) {
            int oc = w * 64 + mt * 16 + kg * 4;
            int px = p0 + nt * 16 + lr;
            float* op = out + (size_t)b * DIM_ * HW_ + (size_t)oc * HW_ + px;
            op[0 * HW_] = acc[mt][nt].x;
            op[1 * HW_] = acc[mt][nt].y;
            op[2 * HW_] = acc[mt][nt].z;
            op[3 * HW_] = acc[mt][nt].w;
        }
    }
}

extern "C" void kernel_launch(void* const* d_in, const int* in_sizes, int n_in,
                              void* d_out, int out_size, void* d_ws, size_t ws_size,
                              hipStream_t stream) {
    const float* q_in  = (const float*)d_in[0];
    const float* kv_in = (const float*)d_in[1];
    const float* Wq    = (const float*)d_in[2];
    const float* Wk    = (const float*)d_in[3];
    const float* Wv    = (const float*)d_in[4];
    const float* Wo    = (const float*)d_in[5];
    float* out = (float*)d_out;

    float* wsf = (float*)d_ws;
    ushort* u     = (ushort*)wsf;
    ushort* WfQh  = u;             // 16384 shorts
    ushort* WfQl  = u + 16384;     // 16384
    ushort* WfKVh = u + 32768;     // 32768 (K: first 16384, V: last 16384)
    ushort* WfKVl = u + 65536;     // 32768
    ushort* WoFh  = u + 98304;     // 16384
    ushort* WoFl  = u + 114688;    // 16384 (ends 131072 sh = 65536 floats)
    size_t tens = (size_t)B_ * HEADS_ * HW_ * HD_;   // 4,194,304 floats
    float* qh = wsf + 65536;
    float* kh = qh + tens;
    float* vv = kh + tens;

    k_prep<<<dim3(192), dim3(256), 0, stream>>>(Wq, Wk, Wv, Wo,
                                                WfQh, WfQl, WfKVh, WfKVl, WoFh, WoFl);
    k_qkv<<<dim3(1536), dim3(256), 0, stream>>>(q_in, kv_in,
                                                WfQh, WfQl, WfKVh, WfKVl, qh, kh, vv);
    k_attn<<<dim3(2048), dim3(256), 0, stream>>>(qh, kh, vv, WoFh, WoFl, out);
}